// Round 10
// baseline (446.073 us; speedup 1.0000x reference)
//
#include <hip/hip_runtime.h>
#include <stdint.h>

#define D 64
constexpr float NEG_SLOPE = 0.2f;
#define NPB_SHIFT 9
#define NPB 512          // nodes per bucket
#define PCHUNK 4096      // edges per partition chunk

// ce[l] = sum_d We_l[d] * ae_l[d]
__global__ void k_ce(const float* __restrict__ We1, const float* __restrict__ ae1,
                     const float* __restrict__ We2, const float* __restrict__ ae2,
                     float* __restrict__ ce){
  int lane = threadIdx.x;
  float p1 = We1[lane] * ae1[lane];
  float p2 = We2[lane] * ae2[lane];
  #pragma unroll
  for (int off = 32; off; off >>= 1){ p1 += __shfl_xor(p1, off); p2 += __shfl_xor(p2, off); }
  if (lane == 0){ ce[0] = p1; ce[1] = p2; }
}

// h = X @ W. W column in 64 VGPRs/lane; x broadcast via WAVE-UNIFORM float4
// loads (no ds_bpermute/readlane in the hot loop — DS pipe was the R8/R9
// bottleneck). 8 rows per wave, 8 indep acc chains.
__global__ __launch_bounds__(256) void k_gemm_dots(
    const float* __restrict__ X, const float* __restrict__ W,
    const float* __restrict__ a_s, const float* __restrict__ a_d,
    float* __restrict__ H, float* __restrict__ asrc, float* __restrict__ adst, int n)
{
  int lane = threadIdx.x & 63;
  int wid  = blockIdx.x * 4 + (threadIdx.x >> 6);
  int nw   = gridDim.x * 4;
  float Wc[64];
  #pragma unroll
  for (int k = 0; k < 64; ++k) Wc[k] = W[k * D + lane];   // coalesced, once
  float asv = a_s[lane], adv = a_d[lane];
  int ngrp = (n + 7) >> 3;
  for (int g = wid; g < ngrp; g += nw){
    int r0 = g << 3;
    if (r0 + 8 <= n){
      float acc[8];
      #pragma unroll
      for (int j = 0; j < 8; ++j) acc[j] = 0.f;
      #pragma unroll
      for (int kb = 0; kb < 16; ++kb){
        float4 xv[8];
        #pragma unroll
        for (int j = 0; j < 8; ++j)
          xv[j] = *(const float4*)(X + (size_t)(r0 + j) * D + kb * 4);  // uniform addr
        #pragma unroll
        for (int j = 0; j < 8; ++j){
          acc[j] = fmaf(xv[j].x, Wc[kb * 4 + 0], acc[j]);
          acc[j] = fmaf(xv[j].y, Wc[kb * 4 + 1], acc[j]);
          acc[j] = fmaf(xv[j].z, Wc[kb * 4 + 2], acc[j]);
          acc[j] = fmaf(xv[j].w, Wc[kb * 4 + 3], acc[j]);
        }
      }
      #pragma unroll
      for (int j = 0; j < 8; ++j) H[(size_t)(r0 + j) * D + lane] = acc[j];
      #pragma unroll
      for (int j = 0; j < 8; ++j){
        float ps = acc[j] * asv, pd = acc[j] * adv;
        #pragma unroll
        for (int off = 32; off; off >>= 1){ ps += __shfl_xor(ps, off); pd += __shfl_xor(pd, off); }
        if (lane == 0){ asrc[r0 + j] = ps; adst[r0 + j] = pd; }
      }
    } else {
      for (int j = 0; r0 + j < n; ++j){
        float acc = 0.f;
        #pragma unroll
        for (int kb = 0; kb < 16; ++kb){
          float4 xv = *(const float4*)(X + (size_t)(r0 + j) * D + kb * 4);
          acc = fmaf(xv.x, Wc[kb * 4 + 0], acc);
          acc = fmaf(xv.y, Wc[kb * 4 + 1], acc);
          acc = fmaf(xv.z, Wc[kb * 4 + 2], acc);
          acc = fmaf(xv.w, Wc[kb * 4 + 3], acc);
        }
        H[(size_t)(r0 + j) * D + lane] = acc;
        float ps = acc * asv, pd = acc * adv;
        #pragma unroll
        for (int off = 32; off; off >>= 1){ ps += __shfl_xor(ps, off); pd += __shfl_xor(pd, off); }
        if (lane == 0){ asrc[r0 + j] = ps; adst[r0 + j] = pd; }
      }
    }
  }
}

// ---------------- contention-free CSR build ----------------

// per-chunk bucket histogram -> C[b*nchunk + c]  (no global atomics)
__global__ __launch_bounds__(256) void k_bhist(const int* __restrict__ dst,
    int* __restrict__ C, int nchunk, int e, int nbkt){
  __shared__ int hist[256];
  int tid = threadIdx.x, c = blockIdx.x;
  if (tid < nbkt) hist[tid] = 0;
  __syncthreads();
  int c0 = c * PCHUNK;
  #pragma unroll
  for (int k = 0; k < PCHUNK / 256; ++k){
    int i = c0 + tid + (k << 8);
    if (i < e) atomicAdd(&hist[dst[i] >> NPB_SHIFT], 1);
  }
  __syncthreads();
  if (tid < nbkt) C[tid * nchunk + c] = hist[tid];
}

// per-bucket exclusive scan of C over chunks; bucket totals (nchunk <= 512)
__global__ __launch_bounds__(512) void k_cscan(int* __restrict__ C,
    int* __restrict__ btot, int nchunk){
  __shared__ int s[512];
  int b = blockIdx.x, tid = threadIdx.x;
  int v = (tid < nchunk) ? C[b * nchunk + tid] : 0;
  s[tid] = v; __syncthreads();
  #pragma unroll
  for (int off = 1; off < 512; off <<= 1){
    int t = (tid >= off) ? s[tid - off] : 0;
    __syncthreads();
    s[tid] += t;
    __syncthreads();
  }
  if (tid < nchunk) C[b * nchunk + tid] = s[tid] - v;   // exclusive
  if (tid == 511) btot[b] = s[511];
}

// exclusive scan of bucket totals -> gbase[nbkt+1]  (nbkt <= 256)
__global__ __launch_bounds__(256) void k_bscan(const int* __restrict__ btot,
    int* __restrict__ gbase, int nbkt){
  __shared__ int s[256];
  int tid = threadIdx.x;
  int v = (tid < nbkt) ? btot[tid] : 0;
  s[tid] = v; __syncthreads();
  #pragma unroll
  for (int off = 1; off < 256; off <<= 1){
    int t = (tid >= off) ? s[tid - off] : 0;
    __syncthreads();
    s[tid] += t;
    __syncthreads();
  }
  if (tid < nbkt) gbase[tid] = s[tid] - v;
  if (tid == 255) gbase[nbkt] = s[255];
}

// partition edges into dst-buckets at precomputed offsets (zero global atomics)
__global__ __launch_bounds__(256) void k_part(const int* __restrict__ src,
    const int* __restrict__ dst, const float* __restrict__ ea,
    const int* __restrict__ gbase, const int* __restrict__ C, int nchunk,
    int2* __restrict__ staging, int e, int nbkt){
  __shared__ int base[256], cnt[256];
  int tid = threadIdx.x, c = blockIdx.x;
  if (tid < nbkt){ base[tid] = gbase[tid] + C[tid * nchunk + c]; cnt[tid] = 0; }
  __syncthreads();
  int c0 = c * PCHUNK;
  int w0[PCHUNK / 256], w1[PCHUNK / 256], bk[PCHUNK / 256];
  #pragma unroll
  for (int k = 0; k < PCHUNK / 256; ++k){
    int i = c0 + tid + (k << 8);
    bk[k] = -1;
    if (i < e){
      int d = dst[i];
      bk[k] = d >> NPB_SHIFT;
      w0[k] = src[i] | ((d & (NPB - 1)) << 17);   // src<2^17, dloc<2^9
      w1[k] = __float_as_int(ea[i]);
    }
  }
  #pragma unroll
  for (int k = 0; k < PCHUNK / 256; ++k){
    if (bk[k] >= 0){
      int pos = base[bk[k]] + atomicAdd(&cnt[bk[k]], 1);
      staging[pos] = make_int2(w0[k], w1[k]);
    }
  }
}

// one block per bucket: LDS node histogram + scan -> rowptr; permute edges
// into exact CSR positions inside the bucket's 64KB window (single CU/XCD)
__global__ __launch_bounds__(512) void k_bucket(const int* __restrict__ gbase,
    const int2* __restrict__ staging, int2* __restrict__ edges,
    int* __restrict__ rowptr, int n, int nbkt){
  __shared__ int degL[NPB], sc[NPB];
  int b = blockIdx.x, tid = threadIdx.x;
  int node0 = b << NPB_SHIFT;
  int nn = min(NPB, n - node0);
  int base = gbase[b], endj = gbase[b + 1];
  degL[tid] = 0;
  __syncthreads();
  for (int j = base + tid; j < endj; j += NPB)
    atomicAdd(&degL[staging[j].x >> 17], 1);
  __syncthreads();
  int dv = degL[tid];
  sc[tid] = dv;
  __syncthreads();
  #pragma unroll
  for (int off = 1; off < NPB; off <<= 1){
    int t = (tid >= off) ? sc[tid - off] : 0;
    __syncthreads();
    sc[tid] += t;
    __syncthreads();
  }
  int ex = sc[tid] - dv;                 // exclusive start (local)
  if (tid < nn) rowptr[node0 + tid] = base + ex;
  if (b == nbkt - 1 && tid == 0) rowptr[n] = base + sc[NPB - 1];
  __syncthreads();
  degL[tid] = ex;                        // becomes per-node cursor
  __syncthreads();
  for (int j = base + tid; j < endj; j += NPB){
    int2 w = staging[j];
    int dloc = w.x >> 17;
    int pos = base + atomicAdd(&degL[dloc], 1);
    edges[pos] = make_int2(w.x & 0x1FFFF, w.y);
  }
}

// ---------------- fused per-node softmax + aggregation ----------------
// wave per node, lane=feature. Gather loop 8-way unrolled: 8 independent
// loads in flight per iteration (addresses from shfl of loop-invariant regs).
__global__ __launch_bounds__(256) void k_node_fused(
    const int* __restrict__ rowptr, const int2* __restrict__ edges,
    const float* __restrict__ asrc, const float* __restrict__ adst,
    const float* __restrict__ ce, int ce_idx,
    const float* __restrict__ H, const float* __restrict__ bias,
    float* __restrict__ out, int n, int relu)
{
  int v = blockIdx.x * 4 + (threadIdx.x >> 6);
  int lane = threadIdx.x & 63;
  if (v >= n) return;
  int start = rowptr[v], end = rowptr[v + 1];
  int deg = end - start;
  float bv = bias[lane];
  if (deg == 0){
    float r = relu ? fmaxf(bv, 0.f) : bv;
    out[(size_t)v * D + lane] = r;
    return;
  }
  float adv = adst[v];
  float cev = ce[ce_idx];
  float acc0 = 0.f, acc1 = 0.f, acc2 = 0.f, acc3 = 0.f;
  float inv;
  if (deg <= 64){
    int my_s = 0; float my_a = -1e30f;
    if (lane < deg){
      int2 pr = edges[start + lane];
      my_s = pr.x;
      float a = asrc[pr.x] + adv + __int_as_float(pr.y) * cev;
      my_a = a > 0.f ? a : NEG_SLOPE * a;
    }
    float m = my_a;
    #pragma unroll
    for (int off = 32; off; off >>= 1) m = fmaxf(m, __shfl_xor(m, off));
    float my_e = (lane < deg) ? __expf(my_a - m) : 0.f;
    float ss = my_e;
    #pragma unroll
    for (int off = 32; off; off >>= 1) ss += __shfl_xor(ss, off);
    inv = 1.f / (ss + 1e-16f);
    int k = 0;
    for (; k + 8 <= deg; k += 8){
      int s0 = __shfl(my_s, k+0), s1 = __shfl(my_s, k+1);
      int s2 = __shfl(my_s, k+2), s3 = __shfl(my_s, k+3);
      int s4 = __shfl(my_s, k+4), s5 = __shfl(my_s, k+5);
      int s6 = __shfl(my_s, k+6), s7 = __shfl(my_s, k+7);
      float w0 = __shfl(my_e, k+0), w1 = __shfl(my_e, k+1);
      float w2 = __shfl(my_e, k+2), w3 = __shfl(my_e, k+3);
      float w4 = __shfl(my_e, k+4), w5 = __shfl(my_e, k+5);
      float w6 = __shfl(my_e, k+6), w7 = __shfl(my_e, k+7);
      float h0 = H[(size_t)s0 * D + lane];
      float h1 = H[(size_t)s1 * D + lane];
      float h2 = H[(size_t)s2 * D + lane];
      float h3 = H[(size_t)s3 * D + lane];
      float h4 = H[(size_t)s4 * D + lane];
      float h5 = H[(size_t)s5 * D + lane];
      float h6 = H[(size_t)s6 * D + lane];
      float h7 = H[(size_t)s7 * D + lane];
      acc0 = fmaf(h0, w0, acc0); acc1 = fmaf(h1, w1, acc1);
      acc2 = fmaf(h2, w2, acc2); acc3 = fmaf(h3, w3, acc3);
      acc0 = fmaf(h4, w4, acc0); acc1 = fmaf(h5, w5, acc1);
      acc2 = fmaf(h6, w6, acc2); acc3 = fmaf(h7, w7, acc3);
    }
    for (; k + 2 <= deg; k += 2){
      int s0 = __shfl(my_s, k+0), s1 = __shfl(my_s, k+1);
      float w0 = __shfl(my_e, k+0), w1 = __shfl(my_e, k+1);
      float h0 = H[(size_t)s0 * D + lane];
      float h1 = H[(size_t)s1 * D + lane];
      acc0 = fmaf(h0, w0, acc0); acc1 = fmaf(h1, w1, acc1);
    }
    if (k < deg){
      int s0 = __shfl(my_s, k);
      float w0 = __shfl(my_e, k);
      acc0 = fmaf(H[(size_t)s0 * D + lane], w0, acc0);
    }
  } else {
    float m = -1e30f;
    for (int j = start + lane; j < end; j += 64){
      int2 pr = edges[j];
      float a = asrc[pr.x] + adv + __int_as_float(pr.y) * cev;
      a = a > 0.f ? a : NEG_SLOPE * a;
      m = fmaxf(m, a);
    }
    #pragma unroll
    for (int off = 32; off; off >>= 1) m = fmaxf(m, __shfl_xor(m, off));
    float ss = 0.f;
    for (int j0 = start; j0 < end; j0 += 64){
      int j = j0 + lane;
      int my_s = 0; float my_e = 0.f;
      if (j < end){
        int2 pr = edges[j];
        float a = asrc[pr.x] + adv + __int_as_float(pr.y) * cev;
        a = a > 0.f ? a : NEG_SLOPE * a;
        my_e = __expf(a - m);
        my_s = pr.x;
      }
      ss += my_e;
      int cnt = min(64, end - j0);
      int k = 0;
      for (; k + 4 <= cnt; k += 4){
        int s0 = __shfl(my_s, k+0), s1 = __shfl(my_s, k+1);
        int s2 = __shfl(my_s, k+2), s3 = __shfl(my_s, k+3);
        float w0 = __shfl(my_e, k+0), w1 = __shfl(my_e, k+1);
        float w2 = __shfl(my_e, k+2), w3 = __shfl(my_e, k+3);
        float h0 = H[(size_t)s0 * D + lane];
        float h1 = H[(size_t)s1 * D + lane];
        float h2 = H[(size_t)s2 * D + lane];
        float h3 = H[(size_t)s3 * D + lane];
        acc0 = fmaf(h0, w0, acc0); acc1 = fmaf(h1, w1, acc1);
        acc2 = fmaf(h2, w2, acc2); acc3 = fmaf(h3, w3, acc3);
      }
      for (; k < cnt; ++k){
        int s0 = __shfl(my_s, k);
        float w0 = __shfl(my_e, k);
        acc0 = fmaf(H[(size_t)s0 * D + lane], w0, acc0);
      }
    }
    #pragma unroll
    for (int off = 32; off; off >>= 1) ss += __shfl_xor(ss, off);
    inv = 1.f / (ss + 1e-16f);
  }
  float acc = (acc0 + acc1) + (acc2 + acc3);
  float r = acc * inv + bv;
  if (relu) r = fmaxf(r, 0.f);
  out[(size_t)v * D + lane] = r;
}

extern "C" void kernel_launch(void* const* d_in, const int* in_sizes, int n_in,
                              void* d_out, int out_size, void* d_ws, size_t ws_size,
                              hipStream_t stream)
{
  const float* x    = (const float*)d_in[0];
  const int*   ei   = (const int*)d_in[1];    // integer inputs arrive as int32
  const float* ea   = (const float*)d_in[2];
  const float* W1   = (const float*)d_in[3];
  const float* We1  = (const float*)d_in[4];
  const float* as1  = (const float*)d_in[5];
  const float* ad1  = (const float*)d_in[6];
  const float* ae1  = (const float*)d_in[7];
  const float* b1   = (const float*)d_in[8];
  const float* W2   = (const float*)d_in[9];
  const float* We2  = (const float*)d_in[10];
  const float* as2  = (const float*)d_in[11];
  const float* ad2  = (const float*)d_in[12];
  const float* ae2  = (const float*)d_in[13];
  const float* b2   = (const float*)d_in[14];
  float* out = (float*)d_out;

  int n = in_sizes[0] / D;     // 100000
  int e = in_sizes[1] / 2;     // 1600000
  const int* srcp = ei;
  const int* dstp = ei + e;

  int nbkt   = (n + NPB - 1) / NPB;          // 196
  int nchunk = (e + PCHUNK - 1) / PCHUNK;    // 391  (must be <= 512)

  char* p = (char*)d_ws;
  float* buf_h   = (float*)p;  p += (size_t)n * D * 4;
  float* buf_x2  = (float*)p;  p += (size_t)n * D * 4;
  float* asrc    = (float*)p;  p += (size_t)n * 4;
  float* adst    = (float*)p;  p += (size_t)n * 4;
  int*   rowptr  = (int*)p;    p += (size_t)(n + 16) * 4;
  int*   gbase   = (int*)p;    p += (size_t)(nbkt + 4) * 4;
  int*   btot    = (int*)p;    p += (size_t)(nbkt + 4) * 4;
  int*   C       = (int*)p;    p += (size_t)nbkt * nchunk * 4;
  float* ce      = (float*)p;  p += 64;
  int2*  edges   = (int2*)p;   p += (size_t)e * 8;
  // staging aliases buf_x2: consumed by k_bucket before layer-1 writes buf_x2
  int2*  staging = (int2*)buf_x2;

  int gR = (n + 3) / 4;       // wave per node, 4 per block
  int gG = ((n + 7) / 8 + 3) / 4;   // gemm: one 8-row group per wave

  // ---- CSR build (contention-free radix partition) ----
  k_ce<<<1, 64, 0, stream>>>(We1, ae1, We2, ae2, ce);
  k_bhist<<<nchunk, 256, 0, stream>>>(dstp, C, nchunk, e, nbkt);
  k_cscan<<<nbkt, 512, 0, stream>>>(C, btot, nchunk);
  k_bscan<<<1, 256, 0, stream>>>(btot, gbase, nbkt);
  k_part<<<nchunk, 256, 0, stream>>>(srcp, dstp, ea, gbase, C, nchunk, staging, e, nbkt);
  k_bucket<<<nbkt, NPB, 0, stream>>>(gbase, staging, edges, rowptr, n, nbkt);

  // ---- layer 1 ----
  k_gemm_dots<<<gG, 256, 0, stream>>>(x, W1, as1, ad1, buf_h, asrc, adst, n);
  k_node_fused<<<gR, 256, 0, stream>>>(rowptr, edges, asrc, adst, ce, 0, buf_h, b1, buf_x2, n, 1);

  // ---- layer 2 ----
  k_gemm_dots<<<gG, 256, 0, stream>>>(buf_x2, W2, as2, ad2, buf_h, asrc, adst, n);
  k_node_fused<<<gR, 256, 0, stream>>>(rowptr, edges, asrc, adst, ce, 1, buf_h, b2, out, n, 0);
}

// Round 11
// 338.573 us; speedup vs baseline: 1.3175x; 1.3175x over previous
//
#include <hip/hip_runtime.h>
#include <stdint.h>

#define D 64
constexpr float NEG_SLOPE = 0.2f;
#define NPB_SHIFT 9
#define NPB 512          // nodes per bucket
#define PCHUNK 4096      // edges per partition chunk

// ce[l] = sum_d We_l[d] * ae_l[d]
__global__ void k_ce(const float* __restrict__ We1, const float* __restrict__ ae1,
                     const float* __restrict__ We2, const float* __restrict__ ae2,
                     float* __restrict__ ce){
  int lane = threadIdx.x;
  float p1 = We1[lane] * ae1[lane];
  float p2 = We2[lane] * ae2[lane];
  #pragma unroll
  for (int off = 32; off; off >>= 1){ p1 += __shfl_xor(p1, off); p2 += __shfl_xor(p2, off); }
  if (lane == 0){ ce[0] = p1; ce[1] = p2; }
}

// h = X @ W. W column in 64 VGPRs/lane. x broadcast via wave-private LDS
// tile: coalesced vector-load staging, then uniform-address ds_read_b128
// (4 MACs per DS op, broadcast = conflict-free). No SMEM, no bpermute in
// the hot loop (R8/R9/R10 post-mortems: those pipes were the bottleneck).
__global__ __launch_bounds__(256) void k_gemm_dots(
    const float* __restrict__ X, const float* __restrict__ W,
    const float* __restrict__ a_s, const float* __restrict__ a_d,
    float* __restrict__ H, float* __restrict__ asrc, float* __restrict__ adst, int n)
{
  __shared__ float sX[4 * 512];          // 2KB per wave, wave-private
  int lane = threadIdx.x & 63;
  int wv   = threadIdx.x >> 6;
  float* tile = sX + wv * 512;
  int wid  = blockIdx.x * 4 + wv;
  int nw   = gridDim.x * 4;
  float Wc[64];
  #pragma unroll
  for (int k = 0; k < 64; ++k) Wc[k] = W[k * D + lane];   // coalesced, once
  float asv = a_s[lane], adv = a_d[lane];
  int ngrp = (n + 7) >> 3;
  for (int g = wid; g < ngrp; g += nw){
    int r0 = g << 3;
    if (r0 + 8 <= n){
      const float4* Xg = (const float4*)(X + (size_t)r0 * D);
      // stage 8x64 tile: lane -> 32B, coalesced global, wave-private LDS
      float4 t0 = Xg[lane * 2], t1 = Xg[lane * 2 + 1];
      ((float4*)tile)[lane * 2]     = t0;
      ((float4*)tile)[lane * 2 + 1] = t1;
      __builtin_amdgcn_wave_barrier();   // order LDS writes before reads (same wave)
      float acc[8];
      #pragma unroll
      for (int j = 0; j < 8; ++j) acc[j] = 0.f;
      #pragma unroll
      for (int j = 0; j < 8; ++j){
        #pragma unroll
        for (int kb = 0; kb < 16; ++kb){
          float4 xv = ((const float4*)(tile + j * 64))[kb];  // uniform ds_read_b128
          acc[j] = fmaf(xv.x, Wc[kb * 4 + 0], acc[j]);
          acc[j] = fmaf(xv.y, Wc[kb * 4 + 1], acc[j]);
          acc[j] = fmaf(xv.z, Wc[kb * 4 + 2], acc[j]);
          acc[j] = fmaf(xv.w, Wc[kb * 4 + 3], acc[j]);
        }
      }
      #pragma unroll
      for (int j = 0; j < 8; ++j) H[(size_t)(r0 + j) * D + lane] = acc[j];
      #pragma unroll
      for (int j = 0; j < 8; ++j){
        float ps = acc[j] * asv, pd = acc[j] * adv;
        #pragma unroll
        for (int off = 32; off; off >>= 1){ ps += __shfl_xor(ps, off); pd += __shfl_xor(pd, off); }
        if (lane == 0){ asrc[r0 + j] = ps; adst[r0 + j] = pd; }
      }
    } else {
      for (int j = 0; r0 + j < n; ++j){
        float acc = 0.f;
        #pragma unroll
        for (int kb = 0; kb < 16; ++kb){
          float4 xv = *(const float4*)(X + (size_t)(r0 + j) * D + kb * 4);
          acc = fmaf(xv.x, Wc[kb * 4 + 0], acc);
          acc = fmaf(xv.y, Wc[kb * 4 + 1], acc);
          acc = fmaf(xv.z, Wc[kb * 4 + 2], acc);
          acc = fmaf(xv.w, Wc[kb * 4 + 3], acc);
        }
        H[(size_t)(r0 + j) * D + lane] = acc;
        float ps = acc * asv, pd = acc * adv;
        #pragma unroll
        for (int off = 32; off; off >>= 1){ ps += __shfl_xor(ps, off); pd += __shfl_xor(pd, off); }
        if (lane == 0){ asrc[r0 + j] = ps; adst[r0 + j] = pd; }
      }
    }
  }
}

// ---------------- contention-free CSR build ----------------

// per-chunk bucket histogram -> C[b*nchunk + c]  (no global atomics)
__global__ __launch_bounds__(256) void k_bhist(const int* __restrict__ dst,
    int* __restrict__ C, int nchunk, int e, int nbkt){
  __shared__ int hist[256];
  int tid = threadIdx.x, c = blockIdx.x;
  if (tid < nbkt) hist[tid] = 0;
  __syncthreads();
  int c0 = c * PCHUNK;
  #pragma unroll
  for (int k = 0; k < PCHUNK / 256; ++k){
    int i = c0 + tid + (k << 8);
    if (i < e) atomicAdd(&hist[dst[i] >> NPB_SHIFT], 1);
  }
  __syncthreads();
  if (tid < nbkt) C[tid * nchunk + c] = hist[tid];
}

// per-bucket exclusive scan of C over chunks; bucket totals (nchunk <= 512)
__global__ __launch_bounds__(512) void k_cscan(int* __restrict__ C,
    int* __restrict__ btot, int nchunk){
  __shared__ int s[512];
  int b = blockIdx.x, tid = threadIdx.x;
  int v = (tid < nchunk) ? C[b * nchunk + tid] : 0;
  s[tid] = v; __syncthreads();
  #pragma unroll
  for (int off = 1; off < 512; off <<= 1){
    int t = (tid >= off) ? s[tid - off] : 0;
    __syncthreads();
    s[tid] += t;
    __syncthreads();
  }
  if (tid < nchunk) C[b * nchunk + tid] = s[tid] - v;   // exclusive
  if (tid == 511) btot[b] = s[511];
}

// exclusive scan of bucket totals -> gbase[nbkt+1]  (nbkt <= 256)
__global__ __launch_bounds__(256) void k_bscan(const int* __restrict__ btot,
    int* __restrict__ gbase, int nbkt){
  __shared__ int s[256];
  int tid = threadIdx.x;
  int v = (tid < nbkt) ? btot[tid] : 0;
  s[tid] = v; __syncthreads();
  #pragma unroll
  for (int off = 1; off < 256; off <<= 1){
    int t = (tid >= off) ? s[tid - off] : 0;
    __syncthreads();
    s[tid] += t;
    __syncthreads();
  }
  if (tid < nbkt) gbase[tid] = s[tid] - v;
  if (tid == 255) gbase[nbkt] = s[255];
}

// partition edges into dst-buckets at precomputed offsets (zero global atomics)
__global__ __launch_bounds__(256) void k_part(const int* __restrict__ src,
    const int* __restrict__ dst, const float* __restrict__ ea,
    const int* __restrict__ gbase, const int* __restrict__ C, int nchunk,
    int2* __restrict__ staging, int e, int nbkt){
  __shared__ int base[256], cnt[256];
  int tid = threadIdx.x, c = blockIdx.x;
  if (tid < nbkt){ base[tid] = gbase[tid] + C[tid * nchunk + c]; cnt[tid] = 0; }
  __syncthreads();
  int c0 = c * PCHUNK;
  int w0[PCHUNK / 256], w1[PCHUNK / 256], bk[PCHUNK / 256];
  #pragma unroll
  for (int k = 0; k < PCHUNK / 256; ++k){
    int i = c0 + tid + (k << 8);
    bk[k] = -1;
    if (i < e){
      int d = dst[i];
      bk[k] = d >> NPB_SHIFT;
      w0[k] = src[i] | ((d & (NPB - 1)) << 17);   // src<2^17, dloc<2^9
      w1[k] = __float_as_int(ea[i]);
    }
  }
  #pragma unroll
  for (int k = 0; k < PCHUNK / 256; ++k){
    if (bk[k] >= 0){
      int pos = base[bk[k]] + atomicAdd(&cnt[bk[k]], 1);
      staging[pos] = make_int2(w0[k], w1[k]);
    }
  }
}

// one block per bucket: LDS node histogram + scan -> rowptr; permute edges
// into exact CSR positions inside the bucket's 64KB window (single CU/XCD)
__global__ __launch_bounds__(512) void k_bucket(const int* __restrict__ gbase,
    const int2* __restrict__ staging, int2* __restrict__ edges,
    int* __restrict__ rowptr, int n, int nbkt){
  __shared__ int degL[NPB], sc[NPB];
  int b = blockIdx.x, tid = threadIdx.x;
  int node0 = b << NPB_SHIFT;
  int nn = min(NPB, n - node0);
  int base = gbase[b], endj = gbase[b + 1];
  degL[tid] = 0;
  __syncthreads();
  for (int j = base + tid; j < endj; j += NPB)
    atomicAdd(&degL[staging[j].x >> 17], 1);
  __syncthreads();
  int dv = degL[tid];
  sc[tid] = dv;
  __syncthreads();
  #pragma unroll
  for (int off = 1; off < NPB; off <<= 1){
    int t = (tid >= off) ? sc[tid - off] : 0;
    __syncthreads();
    sc[tid] += t;
    __syncthreads();
  }
  int ex = sc[tid] - dv;                 // exclusive start (local)
  if (tid < nn) rowptr[node0 + tid] = base + ex;
  if (b == nbkt - 1 && tid == 0) rowptr[n] = base + sc[NPB - 1];
  __syncthreads();
  degL[tid] = ex;                        // becomes per-node cursor
  __syncthreads();
  for (int j = base + tid; j < endj; j += NPB){
    int2 w = staging[j];
    int dloc = w.x >> 17;
    int pos = base + atomicAdd(&degL[dloc], 1);
    edges[pos] = make_int2(w.x & 0x1FFFF, w.y);
  }
}

// ---------------- fused per-node softmax + aggregation ----------------
// wave per node, lane=feature. Gather loop 8-way unrolled: 8 independent
// loads in flight per iteration (addresses from shfl of loop-invariant regs).
__global__ __launch_bounds__(256) void k_node_fused(
    const int* __restrict__ rowptr, const int2* __restrict__ edges,
    const float* __restrict__ asrc, const float* __restrict__ adst,
    const float* __restrict__ ce, int ce_idx,
    const float* __restrict__ H, const float* __restrict__ bias,
    float* __restrict__ out, int n, int relu)
{
  int v = blockIdx.x * 4 + (threadIdx.x >> 6);
  int lane = threadIdx.x & 63;
  if (v >= n) return;
  int start = rowptr[v], end = rowptr[v + 1];
  int deg = end - start;
  float bv = bias[lane];
  if (deg == 0){
    float r = relu ? fmaxf(bv, 0.f) : bv;
    out[(size_t)v * D + lane] = r;
    return;
  }
  float adv = adst[v];
  float cev = ce[ce_idx];
  float acc0 = 0.f, acc1 = 0.f, acc2 = 0.f, acc3 = 0.f;
  float inv;
  if (deg <= 64){
    int my_s = 0; float my_a = -1e30f;
    if (lane < deg){
      int2 pr = edges[start + lane];
      my_s = pr.x;
      float a = asrc[pr.x] + adv + __int_as_float(pr.y) * cev;
      my_a = a > 0.f ? a : NEG_SLOPE * a;
    }
    float m = my_a;
    #pragma unroll
    for (int off = 32; off; off >>= 1) m = fmaxf(m, __shfl_xor(m, off));
    float my_e = (lane < deg) ? __expf(my_a - m) : 0.f;
    float ss = my_e;
    #pragma unroll
    for (int off = 32; off; off >>= 1) ss += __shfl_xor(ss, off);
    inv = 1.f / (ss + 1e-16f);
    int k = 0;
    for (; k + 8 <= deg; k += 8){
      int s0 = __shfl(my_s, k+0), s1 = __shfl(my_s, k+1);
      int s2 = __shfl(my_s, k+2), s3 = __shfl(my_s, k+3);
      int s4 = __shfl(my_s, k+4), s5 = __shfl(my_s, k+5);
      int s6 = __shfl(my_s, k+6), s7 = __shfl(my_s, k+7);
      float w0 = __shfl(my_e, k+0), w1 = __shfl(my_e, k+1);
      float w2 = __shfl(my_e, k+2), w3 = __shfl(my_e, k+3);
      float w4 = __shfl(my_e, k+4), w5 = __shfl(my_e, k+5);
      float w6 = __shfl(my_e, k+6), w7 = __shfl(my_e, k+7);
      float h0 = H[(size_t)s0 * D + lane];
      float h1 = H[(size_t)s1 * D + lane];
      float h2 = H[(size_t)s2 * D + lane];
      float h3 = H[(size_t)s3 * D + lane];
      float h4 = H[(size_t)s4 * D + lane];
      float h5 = H[(size_t)s5 * D + lane];
      float h6 = H[(size_t)s6 * D + lane];
      float h7 = H[(size_t)s7 * D + lane];
      acc0 = fmaf(h0, w0, acc0); acc1 = fmaf(h1, w1, acc1);
      acc2 = fmaf(h2, w2, acc2); acc3 = fmaf(h3, w3, acc3);
      acc0 = fmaf(h4, w4, acc0); acc1 = fmaf(h5, w5, acc1);
      acc2 = fmaf(h6, w6, acc2); acc3 = fmaf(h7, w7, acc3);
    }
    for (; k + 2 <= deg; k += 2){
      int s0 = __shfl(my_s, k+0), s1 = __shfl(my_s, k+1);
      float w0 = __shfl(my_e, k+0), w1 = __shfl(my_e, k+1);
      float h0 = H[(size_t)s0 * D + lane];
      float h1 = H[(size_t)s1 * D + lane];
      acc0 = fmaf(h0, w0, acc0); acc1 = fmaf(h1, w1, acc1);
    }
    if (k < deg){
      int s0 = __shfl(my_s, k);
      float w0 = __shfl(my_e, k);
      acc0 = fmaf(H[(size_t)s0 * D + lane], w0, acc0);
    }
  } else {
    float m = -1e30f;
    for (int j = start + lane; j < end; j += 64){
      int2 pr = edges[j];
      float a = asrc[pr.x] + adv + __int_as_float(pr.y) * cev;
      a = a > 0.f ? a : NEG_SLOPE * a;
      m = fmaxf(m, a);
    }
    #pragma unroll
    for (int off = 32; off; off >>= 1) m = fmaxf(m, __shfl_xor(m, off));
    float ss = 0.f;
    for (int j0 = start; j0 < end; j0 += 64){
      int j = j0 + lane;
      int my_s = 0; float my_e = 0.f;
      if (j < end){
        int2 pr = edges[j];
        float a = asrc[pr.x] + adv + __int_as_float(pr.y) * cev;
        a = a > 0.f ? a : NEG_SLOPE * a;
        my_e = __expf(a - m);
        my_s = pr.x;
      }
      ss += my_e;
      int cnt = min(64, end - j0);
      int k = 0;
      for (; k + 4 <= cnt; k += 4){
        int s0 = __shfl(my_s, k+0), s1 = __shfl(my_s, k+1);
        int s2 = __shfl(my_s, k+2), s3 = __shfl(my_s, k+3);
        float w0 = __shfl(my_e, k+0), w1 = __shfl(my_e, k+1);
        float w2 = __shfl(my_e, k+2), w3 = __shfl(my_e, k+3);
        float h0 = H[(size_t)s0 * D + lane];
        float h1 = H[(size_t)s1 * D + lane];
        float h2 = H[(size_t)s2 * D + lane];
        float h3 = H[(size_t)s3 * D + lane];
        acc0 = fmaf(h0, w0, acc0); acc1 = fmaf(h1, w1, acc1);
        acc2 = fmaf(h2, w2, acc2); acc3 = fmaf(h3, w3, acc3);
      }
      for (; k < cnt; ++k){
        int s0 = __shfl(my_s, k);
        float w0 = __shfl(my_e, k);
        acc0 = fmaf(H[(size_t)s0 * D + lane], w0, acc0);
      }
    }
    #pragma unroll
    for (int off = 32; off; off >>= 1) ss += __shfl_xor(ss, off);
    inv = 1.f / (ss + 1e-16f);
  }
  float acc = (acc0 + acc1) + (acc2 + acc3);
  float r = acc * inv + bv;
  if (relu) r = fmaxf(r, 0.f);
  out[(size_t)v * D + lane] = r;
}

extern "C" void kernel_launch(void* const* d_in, const int* in_sizes, int n_in,
                              void* d_out, int out_size, void* d_ws, size_t ws_size,
                              hipStream_t stream)
{
  const float* x    = (const float*)d_in[0];
  const int*   ei   = (const int*)d_in[1];    // integer inputs arrive as int32
  const float* ea   = (const float*)d_in[2];
  const float* W1   = (const float*)d_in[3];
  const float* We1  = (const float*)d_in[4];
  const float* as1  = (const float*)d_in[5];
  const float* ad1  = (const float*)d_in[6];
  const float* ae1  = (const float*)d_in[7];
  const float* b1   = (const float*)d_in[8];
  const float* W2   = (const float*)d_in[9];
  const float* We2  = (const float*)d_in[10];
  const float* as2  = (const float*)d_in[11];
  const float* ad2  = (const float*)d_in[12];
  const float* ae2  = (const float*)d_in[13];
  const float* b2   = (const float*)d_in[14];
  float* out = (float*)d_out;

  int n = in_sizes[0] / D;     // 100000
  int e = in_sizes[1] / 2;     // 1600000
  const int* srcp = ei;
  const int* dstp = ei + e;

  int nbkt   = (n + NPB - 1) / NPB;          // 196
  int nchunk = (e + PCHUNK - 1) / PCHUNK;    // 391  (must be <= 512)

  char* p = (char*)d_ws;
  float* buf_h   = (float*)p;  p += (size_t)n * D * 4;
  float* buf_x2  = (float*)p;  p += (size_t)n * D * 4;
  float* asrc    = (float*)p;  p += (size_t)n * 4;
  float* adst    = (float*)p;  p += (size_t)n * 4;
  int*   rowptr  = (int*)p;    p += (size_t)(n + 16) * 4;
  int*   gbase   = (int*)p;    p += (size_t)(nbkt + 4) * 4;
  int*   btot    = (int*)p;    p += (size_t)(nbkt + 4) * 4;
  int*   C       = (int*)p;    p += (size_t)nbkt * nchunk * 4;
  float* ce      = (float*)p;  p += 64;
  int2*  edges   = (int2*)p;   p += (size_t)e * 8;
  // staging aliases buf_x2: consumed by k_bucket before layer-1 writes buf_x2
  int2*  staging = (int2*)buf_x2;

  int gR = (n + 3) / 4;       // wave per node, 4 per block
  int gG = ((n + 7) / 8 + 3) / 4;   // gemm: one 8-row group per wave

  // ---- CSR build (contention-free radix partition) ----
  k_ce<<<1, 64, 0, stream>>>(We1, ae1, We2, ae2, ce);
  k_bhist<<<nchunk, 256, 0, stream>>>(dstp, C, nchunk, e, nbkt);
  k_cscan<<<nbkt, 512, 0, stream>>>(C, btot, nchunk);
  k_bscan<<<1, 256, 0, stream>>>(btot, gbase, nbkt);
  k_part<<<nchunk, 256, 0, stream>>>(srcp, dstp, ea, gbase, C, nchunk, staging, e, nbkt);
  k_bucket<<<nbkt, NPB, 0, stream>>>(gbase, staging, edges, rowptr, n, nbkt);

  // ---- layer 1 ----
  k_gemm_dots<<<gG, 256, 0, stream>>>(x, W1, as1, ad1, buf_h, asrc, adst, n);
  k_node_fused<<<gR, 256, 0, stream>>>(rowptr, edges, asrc, adst, ce, 0, buf_h, b1, buf_x2, n, 1);

  // ---- layer 2 ----
  k_gemm_dots<<<gG, 256, 0, stream>>>(buf_x2, W2, as2, ad2, buf_h, asrc, adst, n);
  k_node_fused<<<gR, 256, 0, stream>>>(rowptr, edges, asrc, adst, ce, 1, buf_h, b2, out, n, 0);
}